// Round 3
// baseline (2668.857 us; speedup 1.0000x reference)
//
#include <hip/hip_runtime.h>
#include <hip/hip_bf16.h>
#include <cstdio>
#include <cstdint>

#define BS_   128
#define T_    128
#define A_    8
#define D_    128
#define H_    512
#define ROWS_ 1024           // BS*A
#define MTOT_ 131072         // BS*T*A

typedef __hip_bfloat16 bf16;
typedef __attribute__((ext_vector_type(4))) float f32x4;
typedef __attribute__((ext_vector_type(8))) short s16x8;
typedef __attribute__((ext_vector_type(4))) short s16x4;

// async global->LDS, 16B per lane; LDS dest is wave-uniform base + lane*16
__device__ __forceinline__ void async_ld16(const void* g, const void* lds) {
  __builtin_amdgcn_global_load_lds((const __attribute__((address_space(1))) void*)g,
                                   (__attribute__((address_space(3))) void*)lds,
                                   16, 0, 0);
}
__device__ __forceinline__ s16x8 ldg8(const short* p) { return *(const s16x8*)p; }
__device__ __forceinline__ float sigm(float x) { return 1.f / (1.f + __expf(-x)); }

// load 8 consecutive fp32, round to bf16 A-fragment
__device__ __forceinline__ s16x8 cvt8(const float* p) {
  const float4 a = ((const float4*)p)[0];
  const float4 b = ((const float4*)p)[1];
  s16x8 r_;
  r_[0] = __builtin_bit_cast(short, __float2bfloat16(a.x));
  r_[1] = __builtin_bit_cast(short, __float2bfloat16(a.y));
  r_[2] = __builtin_bit_cast(short, __float2bfloat16(a.z));
  r_[3] = __builtin_bit_cast(short, __float2bfloat16(a.w));
  r_[4] = __builtin_bit_cast(short, __float2bfloat16(b.x));
  r_[5] = __builtin_bit_cast(short, __float2bfloat16(b.y));
  r_[6] = __builtin_bit_cast(short, __float2bfloat16(b.z));
  r_[7] = __builtin_bit_cast(short, __float2bfloat16(b.w));
  return r_;
}

// fp32 -> bf16 weight conversion, 4 elts/thread
__global__ __launch_bounds__(256)
void cvt_kernel(const float* __restrict__ src, bf16* __restrict__ dst) {
  const int i = (blockIdx.x * 256 + threadIdx.x) << 2;
  const float4 v = *(const float4*)(src + i);
  s16x4 o;
  o[0] = __builtin_bit_cast(short, __float2bfloat16(v.x));
  o[1] = __builtin_bit_cast(short, __float2bfloat16(v.y));
  o[2] = __builtin_bit_cast(short, __float2bfloat16(v.z));
  o[3] = __builtin_bit_cast(short, __float2bfloat16(v.w));
  *(s16x4*)((short*)dst + i) = o;
}

// ---------------------------------------------------------------------------
// Fully-fused GRU step. 256 blocks = 8 row-groups(128 rows) x 32 j-slices(16).
// Per block LDS (dynamic, 100 KB): Wih slice 48K + Whh slice 48K + W1 slice 4K
// (all pre-converted bf16), rotate-by-(n&7)*16B swizzle applied on the GLOBAL
// side of global_load_lds (linear landing), undone at read -> conflict-free.
// Computes gi (X_t @ Wih^T), gh (h_t @ Whh^T), gates, h_{t+1}, value-head
// partials, and X_{t+1} = relu(obs_{t+1} @ W1^T + b1) for the next step.
// obs is fp32 on the wire: converted to bf16 A-frags in-register in prologue.
// ---------------------------------------------------------------------------
__global__ __launch_bounds__(256, 1)
void step_kernel(const bf16* __restrict__ Wih, const bf16* __restrict__ Whh,
                 const bf16* __restrict__ W1,
                 const float* __restrict__ bih, const float* __restrict__ bhh,
                 const float* __restrict__ b1,  const float* __restrict__ Wv,
                 const float* __restrict__ obs,
                 const bf16* __restrict__ Xin, bf16* __restrict__ Xout,
                 const float* __restrict__ H32in, float* __restrict__ H32out,
                 const bf16* __restrict__ Hbfin, bf16* __restrict__ Hbfout,
                 float* __restrict__ Vws, const int t) {
  extern __shared__ short sm[];
  short* Wihs = sm;              // 48 rows x 512
  short* Whhs = sm + 24576;      // 48 rows x 512
  short* W1s  = sm + 49152;      // 16 rows x 128

  const int bid = blockIdx.x;
  const int rt = bid >> 5, jt = bid & 31;
  const int j0 = jt << 4;
  const int tid = threadIdx.x;
  const int w = tid >> 6, lane = tid & 63;
  const int r = lane & 15, q = lane >> 4;
  const int rw = (rt << 7) + (w << 5);   // this wave's 32 rows

  // ---- stage weight slices (100 x 1KB chunks; c uniform per wave) ----
#pragma unroll
  for (int i = 0; i < 25; ++i) {
    const int c = (i << 2) + w;
    if (c < 48) {
      const int n = c, g = n >> 4;
      async_ld16(Wih + (size_t)((g << 9) + j0 + (n & 15)) * H_
                     + (((lane - (n & 7)) & 63) << 3), &Wihs[c << 9]);
    } else if (c < 96) {
      const int n = c - 48, g = n >> 4;
      async_ld16(Whh + (size_t)((g << 9) + j0 + (n & 15)) * H_
                     + (((lane - (n & 7)) & 63) << 3), &Whhs[n << 9]);
    } else {
      const int cc = c - 96;
      const int srow = (cc << 2) + (lane >> 4);
      const int unit = ((lane & 15) - (srow & 7)) & 15;
      async_ld16(W1 + (size_t)(j0 + srow) * D_ + (unit << 3), &W1s[cc << 9]);
    }
  }

  // ---- prefetch h_old (fp32), biases, obs frags while staging flies ----
  float hold[2][4];
#pragma unroll
  for (int i = 0; i < 2; ++i)
#pragma unroll
    for (int ii = 0; ii < 4; ++ii)
      hold[i][ii] = H32in[(size_t)(rw + (i << 4) + (q << 2) + ii) * H_ + j0 + r];

  const int j = j0 + r;
  const float bR  = bih[j]        + bhh[j];
  const float bZ  = bih[512 + j]  + bhh[512 + j];
  const float bIN = bih[1024 + j];
  const float bHN = bhh[1024 + j];
  const float wvj = Wv[j];
  const float b1j = b1[j];

  const bool doX = (t < T_ - 1);
  s16x8 aob[2][4];
  if (doX) {
#pragma unroll
    for (int i = 0; i < 2; ++i) {
      const int row = rw + (i << 4) + r;
      const size_t ob = (size_t)(row >> 3) * 131072 + (size_t)(t + 1) * 1024
                      + (size_t)(row & 7) * 128 + (q << 3);
#pragma unroll
      for (int kt = 0; kt < 4; ++kt)
        aob[i][kt] = cvt8(obs + ob + (kt << 5));
    }
  }

  __syncthreads();   // staging complete (vmcnt(0) emitted by compiler)

  // ---- main K loop: gi += X_t @ Wih^T, gh += h_t @ Whh^T ----
  f32x4 gia[3][2], gha[3][2];
  const f32x4 vz = {0.f, 0.f, 0.f, 0.f};
#pragma unroll
  for (int g = 0; g < 3; ++g) { gia[g][0] = vz; gia[g][1] = vz;
                                gha[g][0] = vz; gha[g][1] = vz; }

  const short* hbase = (const short*)Hbfin;
  const short* xbase = (const short*)Xin;
  size_t arow[2];
  arow[0] = (size_t)(rw + r) * H_ + (q << 3);
  arow[1] = arow[0] + (size_t)16 * H_;

  s16x8 ah[4][2], ax[4][2];
#pragma unroll
  for (int p = 0; p < 3; ++p)
#pragma unroll
    for (int i = 0; i < 2; ++i) {
      ah[p][i] = ldg8(hbase + arow[i] + (p << 5));
      ax[p][i] = ldg8(xbase + arow[i] + (p << 5));
    }

#pragma unroll
  for (int kt = 0; kt < 16; ++kt) {
    const int cur = kt & 3;
    if (kt < 13) {
      const int np = (kt + 3) & 3;
#pragma unroll
      for (int i = 0; i < 2; ++i) {
        ah[np][i] = ldg8(hbase + arow[i] + ((kt + 3) << 5));
        ax[np][i] = ldg8(xbase + arow[i] + ((kt + 3) << 5));
      }
    }
    const int kk = (kt << 5) + (q << 3);
#pragma unroll
    for (int g = 0; g < 3; ++g) {
      const int n = (g << 4) + r;
      const int pos = (kk + ((n & 7) << 3)) & 511;
      const s16x8 bi = *(const s16x8*)&Wihs[(n << 9) + pos];
      const s16x8 bh = *(const s16x8*)&Whhs[(n << 9) + pos];
#pragma unroll
      for (int i = 0; i < 2; ++i) {
        gia[g][i] = __builtin_amdgcn_mfma_f32_16x16x32_bf16(ax[cur][i], bi, gia[g][i], 0, 0, 0);
        gha[g][i] = __builtin_amdgcn_mfma_f32_16x16x32_bf16(ah[cur][i], bh, gha[g][i], 0, 0, 0);
      }
    }
  }

  // ---- X_{t+1} = relu(obs_{t+1} @ W1^T + b1) ----
  f32x4 xacc[2] = {vz, vz};
  if (doX) {
#pragma unroll
    for (int kt = 0; kt < 4; ++kt) {
      const int pos = ((kt << 5) + (q << 3) + ((r & 7) << 3)) & 127;
      const s16x8 bw = *(const s16x8*)&W1s[(r << 7) + pos];
#pragma unroll
      for (int i = 0; i < 2; ++i)
        xacc[i] = __builtin_amdgcn_mfma_f32_16x16x32_bf16(aob[i][kt], bw, xacc[i], 0, 0, 0);
    }
  }

  // ---- gates, h update, value head, X store ----
  // C/D layout: col = lane&15 (n = gate col j), row-in-tile = q*4+ii (m = h row)
#pragma unroll
  for (int i = 0; i < 2; ++i) {
#pragma unroll
    for (int ii = 0; ii < 4; ++ii) {
      const int row = rw + (i << 4) + (q << 2) + ii;
      const float rr = sigm(gia[0][i][ii] + gha[0][i][ii] + bR);
      const float zz = sigm(gia[1][i][ii] + gha[1][i][ii] + bZ);
      const float nn = tanhf(gia[2][i][ii] + bIN + rr * (gha[2][i][ii] + bHN));
      const float hnew = (1.f - zz) * nn + zz * hold[i][ii];
      const size_t hi = (size_t)row * H_ + j;
      H32out[hi] = hnew;
      Hbfout[hi] = __float2bfloat16(hnew);
      float vp = wvj * hnew;
      vp += __shfl_xor(vp, 1);
      vp += __shfl_xor(vp, 2);
      vp += __shfl_xor(vp, 4);
      vp += __shfl_xor(vp, 8);     // sum over the 16 j-lanes
      if (r == 0) atomicAdd(&Vws[t * ROWS_ + row], vp);
      if (doX) {
        const float xv = fmaxf(xacc[i][ii] + b1j, 0.f);
        Xout[hi] = __float2bfloat16(xv);
      }
    }
  }
}

// X_0 = relu(obs_{t=0} @ W1^T + b1), same partitioning as step_kernel
__global__ __launch_bounds__(256)
void x0_kernel(const float* __restrict__ obs, const bf16* __restrict__ W1,
               const float* __restrict__ b1, bf16* __restrict__ Xout) {
  __shared__ short W1s[2048];
  const int bid = blockIdx.x;
  const int rt = bid >> 5, jt = bid & 31;
  const int j0 = jt << 4;
  const int tid = threadIdx.x;
  const int w = tid >> 6, lane = tid & 63;
  const int r = lane & 15, q = lane >> 4;
  const int rw = (rt << 7) + (w << 5);

  {
    const int cc = w;   // 4 chunks, one per wave
    const int srow = (cc << 2) + (lane >> 4);
    const int unit = ((lane & 15) - (srow & 7)) & 15;
    async_ld16(W1 + (size_t)(j0 + srow) * D_ + (unit << 3), &W1s[cc << 9]);
  }

  s16x8 aob[2][4];
#pragma unroll
  for (int i = 0; i < 2; ++i) {
    const int row = rw + (i << 4) + r;
    const size_t ob = (size_t)(row >> 3) * 131072 + (size_t)(row & 7) * 128 + (q << 3);
#pragma unroll
    for (int kt = 0; kt < 4; ++kt)
      aob[i][kt] = cvt8(obs + ob + (kt << 5));
  }
  __syncthreads();

  const f32x4 vz = {0.f, 0.f, 0.f, 0.f};
  f32x4 xacc[2] = {vz, vz};
#pragma unroll
  for (int kt = 0; kt < 4; ++kt) {
    const int pos = ((kt << 5) + (q << 3) + ((r & 7) << 3)) & 127;
    const s16x8 bw = *(const s16x8*)&W1s[(r << 7) + pos];
#pragma unroll
    for (int i = 0; i < 2; ++i)
      xacc[i] = __builtin_amdgcn_mfma_f32_16x16x32_bf16(aob[i][kt], bw, xacc[i], 0, 0, 0);
  }
  const float b1j = b1[j0 + r];
#pragma unroll
  for (int i = 0; i < 2; ++i)
#pragma unroll
    for (int ii = 0; ii < 4; ++ii) {
      const int row = rw + (i << 4) + (q << 2) + ii;
      Xout[(size_t)row * H_ + j0 + r] =
          __float2bfloat16(fmaxf(xacc[i][ii] + b1j, 0.f));
    }
}

__global__ __launch_bounds__(256)
void init_kernel(float* __restrict__ H32a, bf16* __restrict__ Hbfa,
                 float* __restrict__ Vws, const float* __restrict__ bv) {
  const int i = blockIdx.x * 256 + threadIdx.x;   // 0..524287
  H32a[i] = 0.f;
  Hbfa[i] = __float2bfloat16(0.f);
  if (i < T_ * ROWS_) Vws[i] = bv[0];
}

__global__ __launch_bounds__(256)
void out_kernel(const float* __restrict__ Vws, float* __restrict__ out) {
  const int o = blockIdx.x * 256 + threadIdx.x;   // [bs][T][A] flat
  const int b = o >> 10, tt = (o >> 3) & 127, a = o & 7;
  out[o] = Vws[tt * ROWS_ + (b << 3) + a];
}

extern "C" void kernel_launch(void* const* d_in, const int* in_sizes, int n_in,
                              void* d_out, int out_size, void* d_ws, size_t ws_size,
                              hipStream_t stream) {
  (void)in_sizes; (void)n_in; (void)out_size;
  // reference dtypes are fp32 -> fp32 on the wire (round-2 NaN = bf16 misread)
  const float* obs = (const float*)d_in[0];
  const float* W1  = (const float*)d_in[1];
  const float* b1  = (const float*)d_in[2];
  const float* Wih = (const float*)d_in[3];
  const float* bih = (const float*)d_in[4];
  const float* Whh = (const float*)d_in[5];
  const float* bhh = (const float*)d_in[6];
  const float* Wv  = (const float*)d_in[7];
  const float* bv  = (const float*)d_in[8];
  float* out = (float*)d_out;

  char* ws = (char*)d_ws;
  size_t off = 0;
  bf16*  Xa    = (bf16*)(ws + off);  off += (size_t)ROWS_ * H_ * 2;    // 1 MiB
  bf16*  Xb    = (bf16*)(ws + off);  off += (size_t)ROWS_ * H_ * 2;    // 1 MiB
  float* H32a  = (float*)(ws + off); off += (size_t)ROWS_ * H_ * 4;    // 2 MiB
  float* H32b  = (float*)(ws + off); off += (size_t)ROWS_ * H_ * 4;    // 2 MiB
  bf16*  Hbfa  = (bf16*)(ws + off);  off += (size_t)ROWS_ * H_ * 2;    // 1 MiB
  bf16*  Hbfb  = (bf16*)(ws + off);  off += (size_t)ROWS_ * H_ * 2;    // 1 MiB
  float* Vws   = (float*)(ws + off); off += (size_t)T_ * ROWS_ * 4;    // 0.5 MiB
  bf16*  WihB  = (bf16*)(ws + off);  off += (size_t)3 * H_ * H_ * 2;   // 1.5 MiB
  bf16*  WhhB  = (bf16*)(ws + off);  off += (size_t)3 * H_ * H_ * 2;   // 1.5 MiB
  bf16*  W1B   = (bf16*)(ws + off);  off += (size_t)H_ * D_ * 2;       // 128 KiB
  if (ws_size < off) {
    fprintf(stderr, "[kernel_launch] WS TOO SMALL: need %zu have %zu\n", off, ws_size);
    fflush(stderr);
  }

  hipFuncSetAttribute((const void*)step_kernel,
                      hipFuncAttributeMaxDynamicSharedMemorySize, 102400);

  cvt_kernel<<<768, 256, 0, stream>>>(Wih, WihB);   // 786432 elts
  cvt_kernel<<<768, 256, 0, stream>>>(Whh, WhhB);
  cvt_kernel<<<64, 256, 0, stream>>>(W1, W1B);      // 65536 elts
  init_kernel<<<2048, 256, 0, stream>>>(H32a, Hbfa, Vws, bv);
  x0_kernel<<<256, 256, 0, stream>>>(obs, W1B, b1, Xa);
  for (int t = 0; t < T_; ++t) {
    const float* hin  = (t & 1) ? H32b : H32a;
    float*       hout = (t & 1) ? H32a : H32b;
    const bf16*  hbin = (t & 1) ? Hbfb : Hbfa;
    bf16*        hbout= (t & 1) ? Hbfa : Hbfb;
    const bf16*  xin  = (t & 1) ? Xb : Xa;
    bf16*        xout = (t & 1) ? Xa : Xb;
    step_kernel<<<256, 256, 102400, stream>>>(WihB, WhhB, W1B, bih, bhh, b1, Wv,
                                              obs, xin, xout, hin, hout,
                                              hbin, hbout, Vws, t);
  }
  out_kernel<<<MTOT_ / 256, 256, 0, stream>>>(Vws, out);
}

// Round 4
// 2224.834 us; speedup vs baseline: 1.1996x; 1.1996x over previous
//
#include <hip/hip_runtime.h>
#include <hip/hip_bf16.h>
#include <cstdio>
#include <cstdint>

#define BS_   128
#define T_    128
#define A_    8
#define D_    128
#define H_    512
#define ROWS_ 1024           // BS*A
#define MTOT_ 131072         // BS*T*A
#define SLAB_ (ROWS_ * H_)   // one timestep of X, in elements

typedef __hip_bfloat16 bf16;
typedef __attribute__((ext_vector_type(4))) float f32x4;
typedef __attribute__((ext_vector_type(8))) short s16x8;
typedef __attribute__((ext_vector_type(4))) short s16x4;

// async global->LDS, 16B per lane; LDS dest is wave-uniform base + lane*16
__device__ __forceinline__ void async_ld16(const void* g, const void* lds) {
  __builtin_amdgcn_global_load_lds((const __attribute__((address_space(1))) void*)g,
                                   (__attribute__((address_space(3))) void*)lds,
                                   16, 0, 0);
}
__device__ __forceinline__ s16x8 ldg8(const short* p) { return *(const s16x8*)p; }
__device__ __forceinline__ float sigm(float x) { return 1.f / (1.f + __expf(-x)); }

// fp32 -> bf16 conversion, 4 elts/thread
__global__ __launch_bounds__(256)
void cvt_kernel(const float* __restrict__ src, bf16* __restrict__ dst) {
  const int i = (blockIdx.x * 256 + threadIdx.x) << 2;
  const float4 v = *(const float4*)(src + i);
  s16x4 o;
  o[0] = __builtin_bit_cast(short, __float2bfloat16(v.x));
  o[1] = __builtin_bit_cast(short, __float2bfloat16(v.y));
  o[2] = __builtin_bit_cast(short, __float2bfloat16(v.z));
  o[3] = __builtin_bit_cast(short, __float2bfloat16(v.w));
  *(s16x4*)((short*)dst + i) = o;
}

// ---------------------------------------------------------------------------
// X = relu(obs @ W1^T + b1) for ALL timesteps, stored X[t][row][j] (row=b*8+a).
// m97 recipe: 128x128 tile, BK=32, global_load_lds w16, 4 waves x 4x4 MFMA.
// ---------------------------------------------------------------------------
__global__ __launch_bounds__(256)
void xgemm_kernel(const bf16* __restrict__ Ag, const bf16* __restrict__ Wg,
                  const float* __restrict__ bias, bf16* __restrict__ Og) {
  const int bid = blockIdx.x;
  const int m0 = (bid >> 2) << 7;
  const int n0 = (bid & 3) << 7;
  const int tid = threadIdx.x;
  const int w = tid >> 6, lane = tid & 63;
  const int r = lane & 15, q = lane >> 4;
  const int wm = w & 1, wn = w >> 1;

  __shared__ short As[128 * 32];
  __shared__ short Bs[128 * 32];

  f32x4 acc[4][4];
  const f32x4 vz = {0.f, 0.f, 0.f, 0.f};
#pragma unroll
  for (int i = 0; i < 4; ++i)
#pragma unroll
    for (int j = 0; j < 4; ++j) acc[i][j] = vz;

  const int lrow = lane >> 2;
  const int kcol = (lane & 3) << 3;

  for (int kt = 0; kt < 4; ++kt) {          // K = 128
    __syncthreads();
    const int kbase = kt << 5;
#pragma unroll
    for (int jj = 0; jj < 2; ++jj) {
      const int c = (w << 1) + jj;
      const int m = (c << 4) + lrow;
      async_ld16(Ag + (size_t)(m0 + m) * D_ + kbase + kcol, &As[c << 9]);
      async_ld16(Wg + (size_t)(n0 + m) * D_ + kbase + kcol, &Bs[c << 9]);
    }
    __syncthreads();

    s16x8 af[4], bfr[4];
#pragma unroll
    for (int x = 0; x < 4; ++x) {
      af[x]  = *(const s16x8*)&As[((wm << 6) + (x << 4) + r) * 32 + (q << 3)];
      bfr[x] = *(const s16x8*)&Bs[((wn << 6) + (x << 4) + r) * 32 + (q << 3)];
    }
#pragma unroll
    for (int i = 0; i < 4; ++i)
#pragma unroll
      for (int j = 0; j < 4; ++j)
        acc[i][j] = __builtin_amdgcn_mfma_f32_16x16x32_bf16(af[i], bfr[j],
                                                            acc[i][j], 0, 0, 0);
  }

#pragma unroll
  for (int j = 0; j < 4; ++j) {
    const int gn = n0 + (wn << 6) + (j << 4) + r;
    const float bb = bias[gn];
#pragma unroll
    for (int i = 0; i < 4; ++i) {
      const int gmb = m0 + (wm << 6) + (i << 4) + (q << 2);
#pragma unroll
      for (int ii = 0; ii < 4; ++ii) {
        const int gm = gmb + ii;
        const float v = fmaxf(acc[i][j][ii] + bb, 0.f);
        // gm = ((b*T)+t)*A+a  ->  X[t][b*8+a][gn]
        const int b = gm >> 10, tt = (gm >> 3) & 127, a = gm & 7;
        Og[((size_t)tt * ROWS_ + (b << 3) + a) * (size_t)H_ + gn] =
            __float2bfloat16(v);
      }
    }
  }
}

// 48-col gate GEMM helper: acc[3][2] += A(2x16rows) @ Wlds(48x512)^T, K=512.
// LDS rows carry rotate-by-(n&7)*16B swizzle (applied at global_load_lds time).
__device__ __forceinline__ void mm48(f32x4 acc[3][2], const short* g0,
                                     const short* g1, const short* lds,
                                     const int q, const int r) {
  s16x8 a[4][2];
#pragma unroll
  for (int p = 0; p < 3; ++p) {
    a[p][0] = ldg8(g0 + (p << 5));
    a[p][1] = ldg8(g1 + (p << 5));
  }
#pragma unroll
  for (int kt = 0; kt < 16; ++kt) {
    const int cur = kt & 3;
    if (kt < 13) {
      const int np = (kt + 3) & 3;
      a[np][0] = ldg8(g0 + ((kt + 3) << 5));
      a[np][1] = ldg8(g1 + ((kt + 3) << 5));
    }
    const int kk = (kt << 5) + (q << 3);
#pragma unroll
    for (int g = 0; g < 3; ++g) {
      const int n = (g << 4) + r;
      const int pos = (kk + ((n & 7) << 3)) & 511;
      const s16x8 b = *(const s16x8*)&lds[(n << 9) + pos];
#pragma unroll
      for (int i = 0; i < 2; ++i)
        acc[g][i] = __builtin_amdgcn_mfma_f32_16x16x32_bf16(a[cur][i], b,
                                                            acc[g][i], 0, 0, 0);
    }
  }
}

// ---------------------------------------------------------------------------
// Persistent GRU scan. 256 blocks (=CUs, 96KB LDS forces 1 block/CU so all
// co-resident) x 256 thr. Block (rt=bid&7, jt=bid>>3) owns rows rt*128..+127,
// h-cols jt*16..+15. Wih/Whh slices staged to LDS ONCE. fp32 h-master lives in
// registers (same thread owns same (row,col) every step). Per step: gh from
// barrier-fresh global bf16 h, gates, h-update, v-partial; grid barrier with
// agent release/acquire fences; gi_{t+1} (h-independent) computed between
// arrive and spin to hide barrier latency. rt=bid&7 -> same-rt blocks share an
// XCD under round-robin dispatch (perf heuristic only; fences give correctness).
// ---------------------------------------------------------------------------
__global__ __launch_bounds__(256, 1)
void scan_kernel(const bf16* __restrict__ Wih, const bf16* __restrict__ Whh,
                 const float* __restrict__ bih, const float* __restrict__ bhh,
                 const float* __restrict__ Wv, const bf16* __restrict__ X,
                 bf16* __restrict__ Hb0, bf16* __restrict__ Hb1,
                 float* __restrict__ Vws, unsigned* __restrict__ bar) {
  extern __shared__ short sm[];
  short* Wihs = sm;            // 48 x 512
  short* Whhs = sm + 24576;    // 48 x 512

  const int bid = blockIdx.x;
  const int rt = bid & 7, jt = bid >> 3;
  const int j0 = jt << 4;
  const int tid = threadIdx.x;
  const int w = tid >> 6, lane = tid & 63;
  const int r = lane & 15, q = lane >> 4;
  const int rw = (rt << 7) + (w << 5);   // wave's 32 rows

  // ---- stage weight slices once (96 x 1KB chunks, 24/wave) ----
#pragma unroll
  for (int i = 0; i < 24; ++i) {
    const int c = (i << 2) + w;
    const int n = (c < 48) ? c : (c - 48);
    const int g = n >> 4;
    const bf16* src = ((c < 48) ? Wih : Whh)
                    + (size_t)((g << 9) + j0 + (n & 15)) * H_
                    + (((lane - (n & 7)) & 63) << 3);   // rotate swizzle
    async_ld16(src, ((c < 48) ? Wihs : Whhs) + ((size_t)n << 9));
  }

  const int j = j0 + r;
  const float bR  = bih[j] + bhh[j];
  const float bZ  = bih[512 + j] + bhh[512 + j];
  const float bIN = bih[1024 + j];
  const float bHN = bhh[1024 + j];
  const float wvj = Wv[j];

  float hm[2][4] = {{0.f, 0.f, 0.f, 0.f}, {0.f, 0.f, 0.f, 0.f}};
  const f32x4 vz = {0.f, 0.f, 0.f, 0.f};

  const size_t aoff0 = (size_t)(rw + r) * H_ + (q << 3);
  const size_t aoff1 = aoff0 + (size_t)16 * H_;
  const short* Xs = (const short*)X;

  __syncthreads();   // weights staged (vmcnt(0) before barrier)

  f32x4 gia[3][2];
#pragma unroll
  for (int g = 0; g < 3; ++g) { gia[g][0] = vz; gia[g][1] = vz; }
  mm48(gia, Xs + aoff0, Xs + aoff1, Wihs, q, r);   // gi for t=0

  for (int t = 0; t < T_; ++t) {
    const short* hb = (const short*)((t & 1) ? Hb1 : Hb0);
    short* hn = (short*)((t & 1) ? Hb0 : Hb1);

    f32x4 gha[3][2];
#pragma unroll
    for (int g = 0; g < 3; ++g) { gha[g][0] = vz; gha[g][1] = vz; }
    mm48(gha, hb + aoff0, hb + aoff1, Whhs, q, r);

#pragma unroll
    for (int i = 0; i < 2; ++i)
#pragma unroll
      for (int ii = 0; ii < 4; ++ii) {
        const int row = rw + (i << 4) + (q << 2) + ii;
        const float rr = sigm(gia[0][i][ii] + gha[0][i][ii] + bR);
        const float zz = sigm(gia[1][i][ii] + gha[1][i][ii] + bZ);
        const float nn = tanhf(gia[2][i][ii] + bIN + rr * (gha[2][i][ii] + bHN));
        const float hnew = (1.f - zz) * nn + zz * hm[i][ii];
        hm[i][ii] = hnew;
        hn[(size_t)row * H_ + j] = __builtin_bit_cast(short, __float2bfloat16(hnew));
        float vp = wvj * hnew;
        vp += __shfl_xor(vp, 1);
        vp += __shfl_xor(vp, 2);
        vp += __shfl_xor(vp, 4);
        vp += __shfl_xor(vp, 8);           // sum 16 j-lanes
        if (r == 0) atomicAdd(&Vws[t * ROWS_ + row], vp);
      }

    if (t == T_ - 1) break;

    // ---- grid barrier with gi-overlap ----
    __syncthreads();                                        // h stores done (vmcnt drain)
    if (w == 0) __builtin_amdgcn_fence(__ATOMIC_RELEASE, "agent");  // wbl2: L2->L3
    __syncthreads();                                        // release complete
    if (tid == 0) atomicAdd(bar, 1u);                       // arrive (device-scope)

#pragma unroll
    for (int g = 0; g < 3; ++g) { gia[g][0] = vz; gia[g][1] = vz; }
    mm48(gia, Xs + (size_t)(t + 1) * SLAB_ + aoff0,
              Xs + (size_t)(t + 1) * SLAB_ + aoff1, Wihs, q, r);  // overlap

    if (tid == 0) {
      const unsigned tgt = (unsigned)(t + 1) << 8;          // 256*(t+1)
      unsigned spins = 0;
      while (__hip_atomic_load(bar, __ATOMIC_RELAXED, __HIP_MEMORY_SCOPE_AGENT) < tgt) {
        __builtin_amdgcn_s_sleep(4);
        if (++spins > 5000000u) break;                      // dead-man valve
      }
    }
    __syncthreads();
    if (w == 0) __builtin_amdgcn_fence(__ATOMIC_ACQUIRE, "agent");  // inv L1+L2
    __syncthreads();
  }
}

__global__ __launch_bounds__(256)
void init_kernel(bf16* __restrict__ Hb0, float* __restrict__ Vws,
                 unsigned* __restrict__ bar, const float* __restrict__ bv) {
  const int i = blockIdx.x * 256 + threadIdx.x;   // 0..524287
  Hb0[i] = __float2bfloat16(0.f);
  if (i < T_ * ROWS_) Vws[i] = bv[0];
  if (i == 0) *bar = 0u;
}

__global__ __launch_bounds__(256)
void out_kernel(const float* __restrict__ Vws, float* __restrict__ out) {
  const int o = blockIdx.x * 256 + threadIdx.x;   // [bs][T][A] flat
  const int b = o >> 10, tt = (o >> 3) & 127, a = o & 7;
  out[o] = Vws[tt * ROWS_ + (b << 3) + a];
}

extern "C" void kernel_launch(void* const* d_in, const int* in_sizes, int n_in,
                              void* d_out, int out_size, void* d_ws, size_t ws_size,
                              hipStream_t stream) {
  (void)in_sizes; (void)n_in; (void)out_size;
  const float* obs = (const float*)d_in[0];
  const float* W1  = (const float*)d_in[1];
  const float* b1  = (const float*)d_in[2];
  const float* Wih = (const float*)d_in[3];
  const float* bih = (const float*)d_in[4];
  const float* Whh = (const float*)d_in[5];
  const float* bhh = (const float*)d_in[6];
  const float* Wv  = (const float*)d_in[7];
  const float* bv  = (const float*)d_in[8];
  float* out = (float*)d_out;

  char* ws = (char*)d_ws;
  size_t off = 0;
  bf16*  X    = (bf16*)(ws + off);  off += (size_t)T_ * ROWS_ * H_ * 2;  // 128 MiB
  bf16*  obsB = (bf16*)(ws + off);  off += (size_t)MTOT_ * D_ * 2;       // 32 MiB
  bf16*  Hb0  = (bf16*)(ws + off);  off += (size_t)ROWS_ * H_ * 2;       // 1 MiB
  bf16*  Hb1  = (bf16*)(ws + off);  off += (size_t)ROWS_ * H_ * 2;       // 1 MiB
  float* Vws  = (float*)(ws + off); off += (size_t)T_ * ROWS_ * 4;       // 0.5 MiB
  bf16*  WihB = (bf16*)(ws + off);  off += (size_t)3 * H_ * H_ * 2;      // 1.5 MiB
  bf16*  WhhB = (bf16*)(ws + off);  off += (size_t)3 * H_ * H_ * 2;      // 1.5 MiB
  bf16*  W1B  = (bf16*)(ws + off);  off += (size_t)H_ * D_ * 2;          // 128 KiB
  unsigned* bar = (unsigned*)(ws + off); off += 64;
  if (ws_size < off) {
    fprintf(stderr, "[kernel_launch] WS TOO SMALL: need %zu have %zu\n", off, ws_size);
    fflush(stderr);
  }

  hipFuncSetAttribute((const void*)scan_kernel,
                      hipFuncAttributeMaxDynamicSharedMemorySize, 98304);

  cvt_kernel<<<768, 256, 0, stream>>>(Wih, WihB);        // 786432 elts
  cvt_kernel<<<768, 256, 0, stream>>>(Whh, WhhB);
  cvt_kernel<<<64, 256, 0, stream>>>(W1, W1B);           // 65536 elts
  cvt_kernel<<<16384, 256, 0, stream>>>(obs, obsB);      // 16.8M elts
  init_kernel<<<2048, 256, 0, stream>>>(Hb0, Vws, bar, bv);
  xgemm_kernel<<<4096, 256, 0, stream>>>(obsB, W1B, b1, X);
  scan_kernel<<<256, 256, 98304, stream>>>(WihB, WhhB, bih, bhh, Wv, X,
                                           Hb0, Hb1, Vws, bar);
  out_kernel<<<MTOT_ / 256, 256, 0, stream>>>(Vws, out);
}